// Round 14
// baseline (308.528 us; speedup 1.0000x reference)
//
#include <hip/hip_runtime.h>
#include <hip/hip_fp16.h>

#define N_NODES    100000
#define N_EDGES    1600000
#define NUM_GRAPHS 64
#define F          64
#define EPS        1e-5f
#define DEG_CAP    64
#define NPART      8
#define PART_SZ    (N_NODES / NPART)          // 12500
#define BIN_CAP    262144                     // per-partition pair capacity (exp ~200K)
#define FCHUNK     1024                       // fill2 edges per claimed chunk
#define F2_BLOCKS  1024

typedef __attribute__((ext_vector_type(8))) _Float16 f16x8;
typedef __attribute__((ext_vector_type(4))) float    f32x4;

// ---------------- init: zero cnt / pooled / binCnt / work ----------------
__global__ void k_init(int* cnt, float* pooled, int* binCnt, int* work) {
    int i = blockIdx.x * blockDim.x + threadIdx.x;
    if (i < 3 * NUM_GRAPHS * F) pooled[i] = 0.f;
    if (i < N_NODES) cnt[i] = 0;
    if (i < NPART) { binCnt[i] = 0; work[i] = 0; }
}

// ---------------- phase 1: bin edges by dst partition (dense writes) ----------------
__global__ void k_bin(const int* __restrict__ src, const int* __restrict__ dst,
                      int* __restrict__ binCnt, int2* __restrict__ bins) {
    __shared__ int bcnt[NPART];
    __shared__ int bbase[NPART];
    int t = threadIdx.x;
    if (t < NPART) bcnt[t] = 0;
    __syncthreads();
    size_t e0 = (size_t)blockIdx.x * 1024 + (size_t)t * 4;   // N_EDGES % 4 == 0
    int4 dv = {0, 0, 0, 0}, sv = {0, 0, 0, 0};
    int p0 = 0, p1 = 0, p2 = 0, p3 = 0, r0 = 0, r1 = 0, r2 = 0, r3 = 0;
    bool valid = e0 < N_EDGES;
    if (valid) {
        dv = *(const int4*)(dst + e0);
        sv = *(const int4*)(src + e0);
        p0 = dv.x / PART_SZ; p1 = dv.y / PART_SZ;
        p2 = dv.z / PART_SZ; p3 = dv.w / PART_SZ;
        r0 = atomicAdd(&bcnt[p0], 1);              // LDS atomic: returns in-block rank
        r1 = atomicAdd(&bcnt[p1], 1);
        r2 = atomicAdd(&bcnt[p2], 1);
        r3 = atomicAdd(&bcnt[p3], 1);
    }
    __syncthreads();
    if (t < NPART) bbase[t] = atomicAdd(&binCnt[t], bcnt[t]);   // 8 global atomics/block
    __syncthreads();
    if (valid) {
        bins[(size_t)p0 * BIN_CAP + bbase[p0] + r0] = make_int2(sv.x, dv.x);
        bins[(size_t)p1 * BIN_CAP + bbase[p1] + r1] = make_int2(sv.y, dv.y);
        bins[(size_t)p2 * BIN_CAP + bbase[p2] + r2] = make_int2(sv.z, dv.z);
        bins[(size_t)p3 * BIN_CAP + bbase[p3] + r3] = make_int2(sv.w, dv.w);
    }
}

// ---------------- phase 2: XCD-pinned partition-local scatter ----------------
// Block reads its REAL chiplet id (HW_REG_XCC_ID, verified learn_hip m09) and
// serves that partition; chunks claimed atomically; stealing keeps correctness
// even if XCC distribution is unexpected.
__global__ void k_fill2(const int* __restrict__ binCnt, const int2* __restrict__ bins,
                        int* __restrict__ cnt, int* __restrict__ bucket,
                        int* __restrict__ work) {
    __shared__ int sh_chunk;
    unsigned xcc;
    asm volatile("s_getreg_b32 %0, hwreg(HW_REG_XCC_ID)" : "=s"(xcc));
    int myp = (int)(xcc & (NPART - 1));
    for (int pi = 0; pi < NPART; ++pi) {
        int p = (myp + pi) & (NPART - 1);          // own partition first, then steal
        int n = binCnt[p]; if (n > BIN_CAP) n = BIN_CAP;
        int nchunks = (n + FCHUNK - 1) / FCHUNK;
        const int2* bin = bins + (size_t)p * BIN_CAP;
        while (true) {
            __syncthreads();
            if (threadIdx.x == 0) sh_chunk = atomicAdd(&work[p], 1);
            __syncthreads();
            int c = sh_chunk;
            if (c >= nchunks) break;
            int i0 = c * FCHUNK;
            int i1 = i0 + FCHUNK; if (i1 > n) i1 = n;
            for (int i = i0 + threadIdx.x; i < i1; i += 256) {
                int2 e = bin[i];
                int slot = atomicAdd(&cnt[e.y], 1);        // XCD-local L2 atomic
                if (slot < DEG_CAP) bucket[(size_t)e.y * DEG_CAP + slot] = e.x;
            }
        }
    }
}

// ---------------- MFMA GEMM: hs[r] = fp16((h[r] @ W) * rsqrt(cnt[r]+1)) ----------------
#define N_TILES (N_NODES / 16)                 // 6250
#define GT_BLOCKS ((N_TILES + 3) / 4)          // 1563
__global__ void k_gemm_mfma(const float* __restrict__ h, const float* __restrict__ W,
                            const int* __restrict__ cnt, __half* __restrict__ out) {
    __shared__ _Float16 Wh[64 * 64];
    int t = threadIdx.x;
    for (int i = t; i < 64 * 64; i += 256) Wh[i] = (_Float16)W[i];
    __syncthreads();
    int lane = t & 63, wv = t >> 6;
    int tile = blockIdx.x * 4 + wv;
    if (tile >= N_TILES) return;
    int row0 = tile * 16;
    int r   = lane & 15;
    int g16 = lane >> 4;
    int k0  = g16 * 8;

    f16x8 Bf[4][2];
#pragma unroll
    for (int ct = 0; ct < 4; ++ct)
#pragma unroll
        for (int ck = 0; ck < 2; ++ck)
#pragma unroll
            for (int i = 0; i < 8; ++i)
                Bf[ct][ck][i] = Wh[(32 * ck + k0 + i) * 64 + ct * 16 + r];

    f16x8 Af[2];
#pragma unroll
    for (int ck = 0; ck < 2; ++ck) {
        const float4* x4 = (const float4*)(h + (size_t)(row0 + r) * F + 32 * ck + k0);
        float4 p = x4[0], q = x4[1];
        Af[ck][0] = (_Float16)p.x; Af[ck][1] = (_Float16)p.y;
        Af[ck][2] = (_Float16)p.z; Af[ck][3] = (_Float16)p.w;
        Af[ck][4] = (_Float16)q.x; Af[ck][5] = (_Float16)q.y;
        Af[ck][6] = (_Float16)q.z; Af[ck][7] = (_Float16)q.w;
    }

    f32x4 acc[4];
#pragma unroll
    for (int ct = 0; ct < 4; ++ct) {
        f32x4 z = {0.f, 0.f, 0.f, 0.f};
        acc[ct] = __builtin_amdgcn_mfma_f32_16x16x32_f16(Af[0], Bf[ct][0], z, 0, 0, 0);
        acc[ct] = __builtin_amdgcn_mfma_f32_16x16x32_f16(Af[1], Bf[ct][1], acc[ct], 0, 0, 0);
    }

#pragma unroll
    for (int j = 0; j < 4; ++j) {
        int rr = row0 + 4 * g16 + j;
        float di = rsqrtf((float)cnt[rr] + 1.0f);
#pragma unroll
        for (int ct = 0; ct < 4; ++ct)
            out[(size_t)rr * F + ct * 16 + r] = __float2half(acc[ct][j] * di);
    }
}

__device__ __forceinline__ float2 cvt2(unsigned int u) {
    __half2 h = *reinterpret_cast<__half2*>(&u);
    return __half22float2(h);
}

#define ACC8(u, wt)                                                          \
    {                                                                        \
        float2 p0 = cvt2((u).x), p1 = cvt2((u).y),                           \
               p2 = cvt2((u).z), p3 = cvt2((u).w);                           \
        a0 = fmaf(p0.x, wt, a0); a1 = fmaf(p0.y, wt, a1);                    \
        a2 = fmaf(p1.x, wt, a2); a3 = fmaf(p1.y, wt, a3);                    \
        a4 = fmaf(p2.x, wt, a4); a5 = fmaf(p2.y, wt, a5);                    \
        a6 = fmaf(p3.x, wt, a6); a7 = fmaf(p3.y, wt, a7);                    \
    }

#define RED8(D)                                                              \
    a0 += __shfl_xor(a0, D); a1 += __shfl_xor(a1, D);                        \
    a2 += __shfl_xor(a2, D); a3 += __shfl_xor(a3, D);                        \
    a4 += __shfl_xor(a4, D); a5 += __shfl_xor(a5, D);                        \
    a6 += __shfl_xor(a6, D); a7 += __shfl_xor(a7, D);

// ---------------- fused aggregate + bias + BN + ReLU + pooled reduce(s) ----------------
// 2 dst nodes per wave; 8 unconditional chunk loads in flight (fast path nent<=32).
template<bool WRITE_OUT, bool POOL_X>
__global__ void k_agg_pool(const __half* __restrict__ hs, const int* __restrict__ cnt,
                           const int* __restrict__ bucket,
                           const int* __restrict__ batch,
                           const float* __restrict__ x,
                           const float* __restrict__ b, const float* __restrict__ gamma,
                           const float* __restrict__ beta, const float* __restrict__ mean,
                           const float* __restrict__ var,
                           float* __restrict__ out,
                           float* __restrict__ pooledX, float* __restrict__ pooledV) {
    __shared__ float prowV[8][64];
    __shared__ float prowX[8][64];
    __shared__ int pg[8];
    int w    = threadIdx.x >> 6;
    int lane = threadIdx.x & 63;
    int half = lane & 31;
    int nsel = lane >> 5;
    int esub = half >> 3;
    int q    = half & 7;
    int base = lane & 32;
    int nodeIdx = w * 2 + nsel;
    int d = blockIdx.x * 8 + nodeIdx;          // 12500*8 == N_NODES exactly
    const uint4* hs4 = (const uint4*)hs;

    int cdeg = cnt[d];
    int kk = cdeg > (DEG_CAP - 1) ? (DEG_CAP - 1) : cdeg;
    int nent = kk + 1;
    int ev = d;
    if (half) ev = bucket[(size_t)d * DEG_CAP + half - 1];
    float2 xv = make_float2(0.f, 0.f);
    if (POOL_X) xv = ((const float2*)x)[(size_t)d * 32 + half];
    int g = batch[d];

    int t0 = 0  + esub, t1 = 4  + esub, t2 = 8  + esub, t3 = 12 + esub;
    int t4 = 16 + esub, t5 = 20 + esub, t6 = 24 + esub, t7 = 28 + esub;
    int s0 = __shfl(ev, base + (t0 < nent ? t0 : 0));
    int s1 = __shfl(ev, base + (t1 < nent ? t1 : 0));
    int s2 = __shfl(ev, base + (t2 < nent ? t2 : 0));
    int s3 = __shfl(ev, base + (t3 < nent ? t3 : 0));
    int s4 = __shfl(ev, base + (t4 < nent ? t4 : 0));
    int s5 = __shfl(ev, base + (t5 < nent ? t5 : 0));
    int s6 = __shfl(ev, base + (t6 < nent ? t6 : 0));
    int s7 = __shfl(ev, base + (t7 < nent ? t7 : 0));
    uint4 u0 = hs4[(size_t)s0 * 8 + q];
    uint4 u1 = hs4[(size_t)s1 * 8 + q];
    uint4 u2 = hs4[(size_t)s2 * 8 + q];
    uint4 u3 = hs4[(size_t)s3 * 8 + q];
    uint4 u4 = hs4[(size_t)s4 * 8 + q];
    uint4 u5 = hs4[(size_t)s5 * 8 + q];
    uint4 u6 = hs4[(size_t)s6 * 8 + q];
    uint4 u7 = hs4[(size_t)s7 * 8 + q];
    float a0 = 0.f, a1 = 0.f, a2 = 0.f, a3 = 0.f,
          a4 = 0.f, a5 = 0.f, a6 = 0.f, a7 = 0.f;
    { float wt = t0 < nent ? 1.f : 0.f; ACC8(u0, wt); }
    { float wt = t1 < nent ? 1.f : 0.f; ACC8(u1, wt); }
    { float wt = t2 < nent ? 1.f : 0.f; ACC8(u2, wt); }
    { float wt = t3 < nent ? 1.f : 0.f; ACC8(u3, wt); }
    { float wt = t4 < nent ? 1.f : 0.f; ACC8(u4, wt); }
    { float wt = t5 < nent ? 1.f : 0.f; ACC8(u5, wt); }
    { float wt = t6 < nent ? 1.f : 0.f; ACC8(u6, wt); }
    { float wt = t7 < nent ? 1.f : 0.f; ACC8(u7, wt); }

    if (__any(nent > 32)) {
        int evB = bucket[(size_t)d * DEG_CAP + 31 + half];
        evB = (evB < 0 || evB >= N_NODES) ? 0 : evB;
#pragma unroll
        for (int i = 0; i < 8; ++i) {
            int uu = 4 * i + esub;
            int tt = 32 + uu;
            int sB = __shfl(evB, base + uu);
            uint4 ub = hs4[(size_t)sB * 8 + q];
            float wt = tt < nent ? 1.f : 0.f;
            ACC8(ub, wt);
        }
    }

    RED8(8) RED8(16)
    float4 V0 = make_float4(0.f, 0.f, 0.f, 0.f);
    float4 V1 = make_float4(0.f, 0.f, 0.f, 0.f);
    if (half < 8) {
        float di = rsqrtf((float)cdeg + 1.0f);
        const float4* b4  = (const float4*)b;
        const float4* m4  = (const float4*)mean;
        const float4* v4  = (const float4*)var;
        const float4* g4  = (const float4*)gamma;
        const float4* e4  = (const float4*)beta;
        float4 bb0 = b4[2 * q], bb1 = b4[2 * q + 1];
        float4 mm0 = m4[2 * q], mm1 = m4[2 * q + 1];
        float4 vv0 = v4[2 * q], vv1 = v4[2 * q + 1];
        float4 gg0 = g4[2 * q], gg1 = g4[2 * q + 1];
        float4 ee0 = e4[2 * q], ee1 = e4[2 * q + 1];
        V0.x = fmaxf((di * a0 + bb0.x - mm0.x) * rsqrtf(vv0.x + EPS) * gg0.x + ee0.x, 0.f);
        V0.y = fmaxf((di * a1 + bb0.y - mm0.y) * rsqrtf(vv0.y + EPS) * gg0.y + ee0.y, 0.f);
        V0.z = fmaxf((di * a2 + bb0.z - mm0.z) * rsqrtf(vv0.z + EPS) * gg0.z + ee0.z, 0.f);
        V0.w = fmaxf((di * a3 + bb0.w - mm0.w) * rsqrtf(vv0.w + EPS) * gg0.w + ee0.w, 0.f);
        V1.x = fmaxf((di * a4 + bb1.x - mm1.x) * rsqrtf(vv1.x + EPS) * gg1.x + ee1.x, 0.f);
        V1.y = fmaxf((di * a5 + bb1.y - mm1.y) * rsqrtf(vv1.y + EPS) * gg1.y + ee1.y, 0.f);
        V1.z = fmaxf((di * a6 + bb1.z - mm1.z) * rsqrtf(vv1.z + EPS) * gg1.z + ee1.z, 0.f);
        V1.w = fmaxf((di * a7 + bb1.w - mm1.w) * rsqrtf(vv1.w + EPS) * gg1.w + ee1.w, 0.f);
        if (WRITE_OUT) {
            float4* o4 = (float4*)out;
            o4[(size_t)d * 16 + 2 * q]     = V0;
            o4[(size_t)d * 16 + 2 * q + 1] = V1;
        }
        float4* pv = (float4*)&prowV[nodeIdx][0];
        pv[2 * q]     = V0;
        pv[2 * q + 1] = V1;
    }
    if (POOL_X) {
        prowX[nodeIdx][2 * half]     = xv.x;
        prowX[nodeIdx][2 * half + 1] = xv.y;
    }
    if (half == 0) pg[nodeIdx] = g;
    __syncthreads();

    int f2 = threadIdx.x & 63;
    for (int r = threadIdx.x >> 6; r < 8; r += 4) {
        int gg = pg[r];
        bool first = true;
        for (int r2 = 0; r2 < r; ++r2) if (pg[r2] == gg) first = false;
        if (first) {
            float a = 0.f, bx = 0.f;
            for (int r2 = r; r2 < 8; ++r2)
                if (pg[r2] == gg) { a += prowV[r2][f2]; if (POOL_X) bx += prowX[r2][f2]; }
            atomicAdd(&pooledV[gg * F + f2], a);
            if (POOL_X) atomicAdd(&pooledX[gg * F + f2], bx);
        }
    }
}

// ---------------- head ----------------
__global__ void k_head(const float* __restrict__ pooled, const float* __restrict__ headW,
                       const float* __restrict__ headb, float* __restrict__ out) {
    int idx = blockIdx.x * blockDim.x + threadIdx.x;   // 1024 = 64*16
    if (idx >= NUM_GRAPHS * 16) return;
    int g = idx >> 4, o = idx & 15;
    float acc = 0.f;
#pragma unroll
    for (int l = 0; l < 3; ++l) {
        const float* pl = pooled + (size_t)l * NUM_GRAPHS * F + (size_t)g * F;
        const float* wl = headW + (size_t)l * F * 16;
        float s = 0.f;
        for (int k = 0; k < F; ++k) s += pl[k] * wl[k * 16 + o];
        acc += s + headb[l * 16 + o];
    }
    out[idx] = acc;
}

extern "C" void kernel_launch(void* const* d_in, const int* in_sizes, int n_in,
                              void* d_out, int out_size, void* d_ws, size_t ws_size,
                              hipStream_t stream) {
    const float* x     = (const float*)d_in[0];
    const int*   ei    = (const int*)d_in[1];
    const int*   src   = ei;
    const int*   dst   = ei + N_EDGES;
    const int*   batch = (const int*)d_in[2];
    const float* convW = (const float*)d_in[3];
    const float* convb = (const float*)d_in[4];
    const float* gamma = (const float*)d_in[5];
    const float* beta  = (const float*)d_in[6];
    const float* mean  = (const float*)d_in[7];
    const float* var   = (const float*)d_in[8];
    const float* headW = (const float*)d_in[9];
    const float* headb = (const float*)d_in[10];
    float* out = (float*)d_out;

    char* p = (char*)d_ws;
    int*    cnt    = (int*)p;       p += sizeof(int) * N_NODES;
    int*    bucket = (int*)p;       p += sizeof(int) * (size_t)N_NODES * DEG_CAP;
    __half* hs     = (__half*)p;    p += sizeof(__half) * (size_t)N_NODES * F;
    float*  hA     = (float*)p;     p += sizeof(float) * (size_t)N_NODES * F;
    float*  pooled = (float*)p;     p += sizeof(float) * 3 * NUM_GRAPHS * F;
    int*    binCnt = (int*)p;       p += sizeof(int) * NPART;
    int*    work   = (int*)p;       p += sizeof(int) * NPART;
    int2*   bins   = (int2*)hA;     // alias: bins die before hA is first written

    const int B = 256;
    int gN   = (N_NODES + B - 1) / B;          // 391
    int gAgg = N_NODES / 8;                    // 12500 (2 nodes/wave, 8/block)
    int gBin = (N_EDGES + 1023) / 1024;        // 1563

    k_init <<<gN, B, 0, stream>>>(cnt, pooled, binCnt, work);
    k_bin  <<<gBin, B, 0, stream>>>(src, dst, binCnt, bins);
    k_fill2<<<F2_BLOCKS, B, 0, stream>>>(binCnt, bins, cnt, bucket, work);

    // ----- layer 0 (also pools x into rep0) -----
    k_gemm_mfma<<<GT_BLOCKS, B, 0, stream>>>(x, convW, cnt, hs);
    k_agg_pool<true, true><<<gAgg, B, 0, stream>>>(hs, cnt, bucket, batch, x, convb,
                                                   gamma, beta, mean, var,
                                                   hA, pooled, pooled + NUM_GRAPHS * F);

    // ----- layer 1 -----
    k_gemm_mfma<<<GT_BLOCKS, B, 0, stream>>>(hA, convW + F * F, cnt, hs);
    k_agg_pool<false, false><<<gAgg, B, 0, stream>>>(hs, cnt, bucket, batch, nullptr,
                                                     convb + F, gamma + F, beta + F,
                                                     mean + F, var + F,
                                                     nullptr, nullptr,
                                                     pooled + 2 * NUM_GRAPHS * F);

    // head
    k_head<<<(NUM_GRAPHS * 16 + B - 1) / B, B, 0, stream>>>(pooled, headW, headb, out);
}

// Round 15
// 202.801 us; speedup vs baseline: 1.5213x; 1.5213x over previous
//
#include <hip/hip_runtime.h>
#include <hip/hip_fp16.h>

#define N_NODES    100000
#define N_EDGES    1600000
#define NUM_GRAPHS 64
#define F          64
#define EPS        1e-5f
#define DEG_CAP    64
#define NPART      8
#define PART_SZ    (N_NODES / NPART)          // 12500
#define NCHUNKS    391
#define CHUNK      4096                       // edges per chunk (1024 int4)

typedef __attribute__((ext_vector_type(8))) _Float16 f16x8;
typedef __attribute__((ext_vector_type(4))) float    f32x4;

// ---------------- init: zero cnt / pooled ----------------
__global__ void k_init(int* cnt, float* pooled) {
    int i = blockIdx.x * blockDim.x + threadIdx.x;
    if (i < 3 * NUM_GRAPHS * F) pooled[i] = 0.f;
    if (i < N_NODES) cnt[i] = 0;
}

// ---------------- dst-partitioned bucket fill, int4 edge loads (round-12 version) ----------------
__global__ void k_fill(const int* __restrict__ src, const int* __restrict__ dst,
                       int* __restrict__ cnt, int* __restrict__ bucket) {
    int p     = blockIdx.x & (NPART - 1);
    int chunk = blockIdx.x >> 3;
    int lo = p * PART_SZ, hi = lo + PART_SZ;
    size_t e0 = (size_t)chunk * CHUNK;
    const int4* d4 = (const int4*)(dst + e0);
    int nv = (int)((N_EDGES - e0) >> 2); if (nv > CHUNK / 4) nv = CHUNK / 4;
    for (int i = threadIdx.x; i < nv; i += 256) {
        int4 dv = d4[i];
        size_t eb = e0 + 4 * (size_t)i;
#define DO_EDGE(dd, off)                                                     \
        {                                                                    \
            int d_ = (dd);                                                   \
            if (d_ >= lo && d_ < hi) {                                       \
                int s_ = src[eb + (off)];                                    \
                int slot = atomicAdd(&cnt[d_], 1);                           \
                if (slot < DEG_CAP) bucket[(size_t)d_ * DEG_CAP + slot] = s_;\
            }                                                                \
        }
        DO_EDGE(dv.x, 0) DO_EDGE(dv.y, 1) DO_EDGE(dv.z, 2) DO_EDGE(dv.w, 3)
#undef DO_EDGE
    }
}

// ---------------- MFMA GEMM: hs[r] = fp16((h[r] @ W) * rsqrt(cnt[r]+1)) ----------------
#define N_TILES (N_NODES / 16)                 // 6250
#define GT_BLOCKS ((N_TILES + 3) / 4)          // 1563
__global__ void k_gemm_mfma(const float* __restrict__ h, const float* __restrict__ W,
                            const int* __restrict__ cnt, __half* __restrict__ out) {
    __shared__ _Float16 Wh[64 * 64];
    int t = threadIdx.x;
    for (int i = t; i < 64 * 64; i += 256) Wh[i] = (_Float16)W[i];
    __syncthreads();
    int lane = t & 63, wv = t >> 6;
    int tile = blockIdx.x * 4 + wv;
    if (tile >= N_TILES) return;
    int row0 = tile * 16;
    int r   = lane & 15;
    int g16 = lane >> 4;
    int k0  = g16 * 8;

    f16x8 Bf[4][2];
#pragma unroll
    for (int ct = 0; ct < 4; ++ct)
#pragma unroll
        for (int ck = 0; ck < 2; ++ck)
#pragma unroll
            for (int i = 0; i < 8; ++i)
                Bf[ct][ck][i] = Wh[(32 * ck + k0 + i) * 64 + ct * 16 + r];

    f16x8 Af[2];
#pragma unroll
    for (int ck = 0; ck < 2; ++ck) {
        const float4* x4 = (const float4*)(h + (size_t)(row0 + r) * F + 32 * ck + k0);
        float4 p = x4[0], q = x4[1];
        Af[ck][0] = (_Float16)p.x; Af[ck][1] = (_Float16)p.y;
        Af[ck][2] = (_Float16)p.z; Af[ck][3] = (_Float16)p.w;
        Af[ck][4] = (_Float16)q.x; Af[ck][5] = (_Float16)q.y;
        Af[ck][6] = (_Float16)q.z; Af[ck][7] = (_Float16)q.w;
    }

    f32x4 acc[4];
#pragma unroll
    for (int ct = 0; ct < 4; ++ct) {
        f32x4 z = {0.f, 0.f, 0.f, 0.f};
        acc[ct] = __builtin_amdgcn_mfma_f32_16x16x32_f16(Af[0], Bf[ct][0], z, 0, 0, 0);
        acc[ct] = __builtin_amdgcn_mfma_f32_16x16x32_f16(Af[1], Bf[ct][1], acc[ct], 0, 0, 0);
    }

#pragma unroll
    for (int j = 0; j < 4; ++j) {
        int rr = row0 + 4 * g16 + j;
        float di = rsqrtf((float)cnt[rr] + 1.0f);
#pragma unroll
        for (int ct = 0; ct < 4; ++ct)
            out[(size_t)rr * F + ct * 16 + r] = __float2half(acc[ct][j] * di);
    }
}

__device__ __forceinline__ float2 cvt2(unsigned int u) {
    __half2 h = *reinterpret_cast<__half2*>(&u);
    return __half22float2(h);
}

#define ACC8(u, wt)                                                          \
    {                                                                        \
        float2 p0 = cvt2((u).x), p1 = cvt2((u).y),                           \
               p2 = cvt2((u).z), p3 = cvt2((u).w);                           \
        a0 = fmaf(p0.x, wt, a0); a1 = fmaf(p0.y, wt, a1);                    \
        a2 = fmaf(p1.x, wt, a2); a3 = fmaf(p1.y, wt, a3);                    \
        a4 = fmaf(p2.x, wt, a4); a5 = fmaf(p2.y, wt, a5);                    \
        a6 = fmaf(p3.x, wt, a6); a7 = fmaf(p3.y, wt, a7);                    \
    }

// ---------------- fused aggregate + bias + BN + ReLU + pooled reduce(s) ----------------
// 4 dst nodes per wave (16 lanes each): 16 unconditional chunk loads in flight
// (2 entries x 4 nodes per load). Entries 0..31 held in ev0/ev1 shuffle regs;
// invalid entries select the self row (address-safe) with weight 0.
// Rare deg>31 -> wave-uniform slow path over slots 31..62.
template<bool WRITE_OUT, bool POOL_X>
__global__ void k_agg_pool(const __half* __restrict__ hs, const int* __restrict__ cnt,
                           const int* __restrict__ bucket,
                           const int* __restrict__ batch,
                           const float* __restrict__ x,
                           const float* __restrict__ b, const float* __restrict__ gamma,
                           const float* __restrict__ beta, const float* __restrict__ mean,
                           const float* __restrict__ var,
                           float* __restrict__ out,
                           float* __restrict__ pooledX, float* __restrict__ pooledV) {
    __shared__ float prowV[16][64];
    __shared__ float prowX[16][64];
    __shared__ int pg[16];
    int w    = threadIdx.x >> 6;
    int lane = threadIdx.x & 63;
    int sub  = lane & 15;                      // position within node group
    int nsel = lane >> 4;                      // node 0..3 within wave
    int esel = sub >> 3;                       // entry parity 0/1
    int q    = sub & 7;                        // uint4 index within 128B row
    int base = lane & 48;                      // shfl base of my 16-group
    int nodeIdx = w * 4 + nsel;                // 0..15 within block
    int d = blockIdx.x * 16 + nodeIdx;         // 6250*16 == N_NODES exactly
    const uint4* hs4 = (const uint4*)hs;

    int cdeg = cnt[d];
    int kk = cdeg > (DEG_CAP - 1) ? (DEG_CAP - 1) : cdeg;
    int nentF = kk + 1;                        // self + neighbors, <= 64
    int ev0 = (sub == 0) ? d : bucket[(size_t)d * DEG_CAP + sub - 1];   // entries 0..15
    int ev1 = bucket[(size_t)d * DEG_CAP + 15 + sub];                   // entries 16..31
    float4 xv = make_float4(0.f, 0.f, 0.f, 0.f);
    if (POOL_X) xv = ((const float4*)x)[(size_t)d * 16 + sub];
    int g = batch[d];

    float a0 = 0.f, a1 = 0.f, a2 = 0.f, a3 = 0.f,
          a4 = 0.f, a5 = 0.f, a6 = 0.f, a7 = 0.f;

#define SELA(i) int s##i; float w##i;                                        \
    { int t = 2 * (i) + esel; int c = __shfl(ev0, base + t);                 \
      s##i = (t < nentF) ? c : d; w##i = (t < nentF) ? 1.f : 0.f; }
#define SELB(i) int s##i; float w##i;                                        \
    { int t = 2 * (i) + esel; int c = __shfl(ev1, base + (t - 16));          \
      s##i = (t < nentF) ? c : d; w##i = (t < nentF) ? 1.f : 0.f; }
#define LD(i) uint4 u##i = hs4[(size_t)s##i * 8 + q];

    SELA(0) SELA(1) SELA(2) SELA(3) SELA(4) SELA(5) SELA(6) SELA(7)
    SELB(8) SELB(9) SELB(10) SELB(11) SELB(12) SELB(13) SELB(14) SELB(15)
    LD(0) LD(1) LD(2) LD(3) LD(4) LD(5) LD(6) LD(7)
    LD(8) LD(9) LD(10) LD(11) LD(12) LD(13) LD(14) LD(15)
    ACC8(u0,  w0)  ACC8(u1,  w1)  ACC8(u2,  w2)  ACC8(u3,  w3)
    ACC8(u4,  w4)  ACC8(u5,  w5)  ACC8(u6,  w6)  ACC8(u7,  w7)
    ACC8(u8,  w8)  ACC8(u9,  w9)  ACC8(u10, w10) ACC8(u11, w11)
    ACC8(u12, w12) ACC8(u13, w13) ACC8(u14, w14) ACC8(u15, w15)
#undef SELA
#undef SELB
#undef LD

    if (__any(nentF > 32)) {                   // rare heavy nodes (deg > 31)
        int evA = bucket[(size_t)d * DEG_CAP + 31 + sub];   // entries 32..47
        int evB = bucket[(size_t)d * DEG_CAP + 47 + sub];   // entries 48..63
#pragma unroll
        for (int i = 0; i < 16; ++i) {
            int t = 32 + 2 * i + esel;
            int cA = __shfl(evA, base + ((t - 32) & 15));
            int cB = __shfl(evB, base + ((t - 48) & 15));
            int c = (t < 48) ? cA : cB;
            int s = (t < nentF) ? c : d;
            uint4 uu = hs4[(size_t)s * 8 + q];
            float wt = (t < nentF) ? 1.f : 0.f;
            ACC8(uu, wt);
        }
    }

    // reduce over entry parity: lanes xor 8 (stays within 16-lane group)
    a0 += __shfl_xor(a0, 8); a1 += __shfl_xor(a1, 8);
    a2 += __shfl_xor(a2, 8); a3 += __shfl_xor(a3, 8);
    a4 += __shfl_xor(a4, 8); a5 += __shfl_xor(a5, 8);
    a6 += __shfl_xor(a6, 8); a7 += __shfl_xor(a7, 8);

    if (sub < 8) {                             // lane q holds feats 8q..8q+7
        float di = rsqrtf((float)cdeg + 1.0f);
        const float4* b4  = (const float4*)b;
        const float4* m4  = (const float4*)mean;
        const float4* v4  = (const float4*)var;
        const float4* g4  = (const float4*)gamma;
        const float4* e4  = (const float4*)beta;
        float4 bb0 = b4[2 * q], bb1 = b4[2 * q + 1];
        float4 mm0 = m4[2 * q], mm1 = m4[2 * q + 1];
        float4 vv0 = v4[2 * q], vv1 = v4[2 * q + 1];
        float4 gg0 = g4[2 * q], gg1 = g4[2 * q + 1];
        float4 ee0 = e4[2 * q], ee1 = e4[2 * q + 1];
        float4 V0, V1;
        V0.x = fmaxf((di * a0 + bb0.x - mm0.x) * rsqrtf(vv0.x + EPS) * gg0.x + ee0.x, 0.f);
        V0.y = fmaxf((di * a1 + bb0.y - mm0.y) * rsqrtf(vv0.y + EPS) * gg0.y + ee0.y, 0.f);
        V0.z = fmaxf((di * a2 + bb0.z - mm0.z) * rsqrtf(vv0.z + EPS) * gg0.z + ee0.z, 0.f);
        V0.w = fmaxf((di * a3 + bb0.w - mm0.w) * rsqrtf(vv0.w + EPS) * gg0.w + ee0.w, 0.f);
        V1.x = fmaxf((di * a4 + bb1.x - mm1.x) * rsqrtf(vv1.x + EPS) * gg1.x + ee1.x, 0.f);
        V1.y = fmaxf((di * a5 + bb1.y - mm1.y) * rsqrtf(vv1.y + EPS) * gg1.y + ee1.y, 0.f);
        V1.z = fmaxf((di * a6 + bb1.z - mm1.z) * rsqrtf(vv1.z + EPS) * gg1.z + ee1.z, 0.f);
        V1.w = fmaxf((di * a7 + bb1.w - mm1.w) * rsqrtf(vv1.w + EPS) * gg1.w + ee1.w, 0.f);
        if (WRITE_OUT) {
            float4* o4 = (float4*)out;
            o4[(size_t)d * 16 + 2 * q]     = V0;
            o4[(size_t)d * 16 + 2 * q + 1] = V1;
        }
        float4* pv = (float4*)&prowV[nodeIdx][0];
        pv[2 * q]     = V0;
        pv[2 * q + 1] = V1;
    }
    if (POOL_X) ((float4*)&prowX[nodeIdx][0])[sub] = xv;
    if (sub == 0) pg[nodeIdx] = g;
    __syncthreads();

    int f2 = threadIdx.x & 63;
    for (int r = threadIdx.x >> 6; r < 16; r += 4) {
        int gg = pg[r];
        bool first = true;
        for (int r2 = 0; r2 < r; ++r2) if (pg[r2] == gg) first = false;
        if (first) {                           // one atomic row per distinct graph
            float a = 0.f, bx = 0.f;
            for (int r2 = r; r2 < 16; ++r2)
                if (pg[r2] == gg) { a += prowV[r2][f2]; if (POOL_X) bx += prowX[r2][f2]; }
            atomicAdd(&pooledV[gg * F + f2], a);
            if (POOL_X) atomicAdd(&pooledX[gg * F + f2], bx);
        }
    }
}

// ---------------- head ----------------
__global__ void k_head(const float* __restrict__ pooled, const float* __restrict__ headW,
                       const float* __restrict__ headb, float* __restrict__ out) {
    int idx = blockIdx.x * blockDim.x + threadIdx.x;   // 1024 = 64*16
    if (idx >= NUM_GRAPHS * 16) return;
    int g = idx >> 4, o = idx & 15;
    float acc = 0.f;
#pragma unroll
    for (int l = 0; l < 3; ++l) {
        const float* pl = pooled + (size_t)l * NUM_GRAPHS * F + (size_t)g * F;
        const float* wl = headW + (size_t)l * F * 16;
        float s = 0.f;
        for (int k = 0; k < F; ++k) s += pl[k] * wl[k * 16 + o];
        acc += s + headb[l * 16 + o];
    }
    out[idx] = acc;
}

extern "C" void kernel_launch(void* const* d_in, const int* in_sizes, int n_in,
                              void* d_out, int out_size, void* d_ws, size_t ws_size,
                              hipStream_t stream) {
    const float* x     = (const float*)d_in[0];
    const int*   ei    = (const int*)d_in[1];
    const int*   src   = ei;
    const int*   dst   = ei + N_EDGES;
    const int*   batch = (const int*)d_in[2];
    const float* convW = (const float*)d_in[3];
    const float* convb = (const float*)d_in[4];
    const float* gamma = (const float*)d_in[5];
    const float* beta  = (const float*)d_in[6];
    const float* mean  = (const float*)d_in[7];
    const float* var   = (const float*)d_in[8];
    const float* headW = (const float*)d_in[9];
    const float* headb = (const float*)d_in[10];
    float* out = (float*)d_out;

    char* p = (char*)d_ws;
    int*    cnt    = (int*)p;       p += sizeof(int) * N_NODES;
    int*    bucket = (int*)p;       p += sizeof(int) * (size_t)N_NODES * DEG_CAP;
    __half* hs     = (__half*)p;    p += sizeof(__half) * (size_t)N_NODES * F;
    float*  hA     = (float*)p;     p += sizeof(float) * (size_t)N_NODES * F;
    float*  pooled = (float*)p;     p += sizeof(float) * 3 * NUM_GRAPHS * F;

    const int B = 256;
    int gN   = (N_NODES + B - 1) / B;          // 391
    int gAgg = N_NODES / 16;                   // 6250 (4 nodes/wave, 16/block)

    k_init<<<gN, B, 0, stream>>>(cnt, pooled);
    k_fill<<<NPART * NCHUNKS, B, 0, stream>>>(src, dst, cnt, bucket);

    // ----- layer 0 (also pools x into rep0) -----
    k_gemm_mfma<<<GT_BLOCKS, B, 0, stream>>>(x, convW, cnt, hs);
    k_agg_pool<true, true><<<gAgg, B, 0, stream>>>(hs, cnt, bucket, batch, x, convb,
                                                   gamma, beta, mean, var,
                                                   hA, pooled, pooled + NUM_GRAPHS * F);

    // ----- layer 1 -----
    k_gemm_mfma<<<GT_BLOCKS, B, 0, stream>>>(hA, convW + F * F, cnt, hs);
    k_agg_pool<false, false><<<gAgg, B, 0, stream>>>(hs, cnt, bucket, batch, nullptr,
                                                     convb + F, gamma + F, beta + F,
                                                     mean + F, var + F,
                                                     nullptr, nullptr,
                                                     pooled + 2 * NUM_GRAPHS * F);

    // head
    k_head<<<(NUM_GRAPHS * 16 + B - 1) / B, B, 0, stream>>>(pooled, headW, headb, out);
}

// Round 16
// 165.190 us; speedup vs baseline: 1.8677x; 1.2277x over previous
//
#include <hip/hip_runtime.h>
#include <hip/hip_fp16.h>

#define N_NODES    100000
#define N_EDGES    1600000
#define NUM_GRAPHS 64
#define F          64
#define EPS        1e-5f
#define DEG_CAP    64
#define BIN_NODES  512
#define NBINS      ((N_NODES + BIN_NODES - 1) / BIN_NODES)   // 196
#define BIN_CAP    16000                    // mean load 8192, sigma 90 -> safe
#define KB_BLOCKS  128
#define KB_EDGES   (N_EDGES / KB_BLOCKS)    // 12500 edges per bin block

typedef __attribute__((ext_vector_type(8))) _Float16 f16x8;
typedef __attribute__((ext_vector_type(4))) float    f32x4;

// ---------------- init: zero pooled / binCnt ----------------
__global__ void k_init(float* pooled, int* binCnt) {
    int i = blockIdx.x * blockDim.x + threadIdx.x;
    if (i < 3 * NUM_GRAPHS * F) pooled[i] = 0.f;
    if (i < NBINS) binCnt[i] = 0;
}

// ---------------- phase 1: bin edges by 512-node dst group (dense rank writes) ----------------
__global__ void k_bin(const int* __restrict__ src, const int* __restrict__ dst,
                      int* __restrict__ binCnt, int2* __restrict__ bins) {
    __shared__ int bcnt[NBINS];
    __shared__ int bbase[NBINS];
    __shared__ int brun[NBINS];
    int t = threadIdx.x;
    for (int i = t; i < NBINS; i += 256) bcnt[i] = 0;
    __syncthreads();
    size_t e0 = (size_t)blockIdx.x * KB_EDGES;          // 12500, %4==0
    const int4* d4 = (const int4*)(dst + e0);
    const int4* s4 = (const int4*)(src + e0);
    const int NV = KB_EDGES / 4;                        // 3125
    // pass 1: count
    for (int i = t; i < NV; i += 256) {
        int4 dv = d4[i];
        atomicAdd(&bcnt[dv.x / BIN_NODES], 1);
        atomicAdd(&bcnt[dv.y / BIN_NODES], 1);
        atomicAdd(&bcnt[dv.z / BIN_NODES], 1);
        atomicAdd(&bcnt[dv.w / BIN_NODES], 1);
    }
    __syncthreads();
    for (int i = t; i < NBINS; i += 256) {
        bbase[i] = atomicAdd(&binCnt[i], bcnt[i]);
        brun[i] = 0;
    }
    __syncthreads();
    // pass 2: rank + dense write (per-block window per bin ~ 64 pairs = 512B)
    for (int i = t; i < NV; i += 256) {
        int4 dv = d4[i];
        int4 sv = s4[i];
#define DO_E(dd, ss)                                                         \
        {                                                                    \
            int bn = (dd) / BIN_NODES;                                       \
            int r = atomicAdd(&brun[bn], 1);                                 \
            int off = bbase[bn] + r;                                         \
            if (off < BIN_CAP) bins[(size_t)bn * BIN_CAP + off] = make_int2((ss), (dd)); \
        }
        DO_E(dv.x, sv.x) DO_E(dv.y, sv.y) DO_E(dv.z, sv.z) DO_E(dv.w, sv.w)
#undef DO_E
    }
}

// ---------------- phase 2: LDS-staged bucket build, fully dense global writes ----------------
__global__ void __launch_bounds__(256, 1) k_fill3(const int* __restrict__ binCnt,
                        const int2* __restrict__ bins,
                        int* __restrict__ cnt, int* __restrict__ bucket) {
    __shared__ int lbucket[BIN_NODES * DEG_CAP];        // 128 KiB
    __shared__ int lcnt[BIN_NODES];                     // 2 KiB
    int bn = blockIdx.x;
    int base = bn * BIN_NODES;
    int nnodes = N_NODES - base; if (nnodes > BIN_NODES) nnodes = BIN_NODES;
    int t = threadIdx.x;
    for (int i = t; i < BIN_NODES; i += 256) lcnt[i] = 0;
    __syncthreads();
    int n = binCnt[bn]; if (n > BIN_CAP) n = BIN_CAP;
    const int2* bin = bins + (size_t)bn * BIN_CAP;
    for (int i = t; i < n; i += 256) {
        int2 e = bin[i];
        int slot = atomicAdd(&lcnt[e.y - base], 1);     // LDS atomic
        if (slot < DEG_CAP) lbucket[(e.y - base) * DEG_CAP + slot] = e.x;
    }
    __syncthreads();
    // dense dump: contiguous 256B rows (includes unused slots - agg never reads them)
    int4* gb = (int4*)(bucket + (size_t)base * DEG_CAP);
    const int4* lb = (const int4*)lbucket;
    int nv = nnodes * (DEG_CAP / 4);                    // rows * 16 int4
    for (int i = t; i < nv; i += 256) gb[i] = lb[i];
    for (int i = t; i < nnodes; i += 256) cnt[base + i] = lcnt[i];
}

// ---------------- MFMA GEMM: hs[r] = fp16((h[r] @ W) * rsqrt(cnt[r]+1)) ----------------
#define N_TILES (N_NODES / 16)                 // 6250
#define GT_BLOCKS ((N_TILES + 3) / 4)          // 1563
__global__ void k_gemm_mfma(const float* __restrict__ h, const float* __restrict__ W,
                            const int* __restrict__ cnt, __half* __restrict__ out) {
    __shared__ _Float16 Wh[64 * 64];
    int t = threadIdx.x;
    for (int i = t; i < 64 * 64; i += 256) Wh[i] = (_Float16)W[i];
    __syncthreads();
    int lane = t & 63, wv = t >> 6;
    int tile = blockIdx.x * 4 + wv;
    if (tile >= N_TILES) return;
    int row0 = tile * 16;
    int r   = lane & 15;
    int g16 = lane >> 4;
    int k0  = g16 * 8;

    f16x8 Bf[4][2];
#pragma unroll
    for (int ct = 0; ct < 4; ++ct)
#pragma unroll
        for (int ck = 0; ck < 2; ++ck)
#pragma unroll
            for (int i = 0; i < 8; ++i)
                Bf[ct][ck][i] = Wh[(32 * ck + k0 + i) * 64 + ct * 16 + r];

    f16x8 Af[2];
#pragma unroll
    for (int ck = 0; ck < 2; ++ck) {
        const float4* x4 = (const float4*)(h + (size_t)(row0 + r) * F + 32 * ck + k0);
        float4 p = x4[0], q = x4[1];
        Af[ck][0] = (_Float16)p.x; Af[ck][1] = (_Float16)p.y;
        Af[ck][2] = (_Float16)p.z; Af[ck][3] = (_Float16)p.w;
        Af[ck][4] = (_Float16)q.x; Af[ck][5] = (_Float16)q.y;
        Af[ck][6] = (_Float16)q.z; Af[ck][7] = (_Float16)q.w;
    }

    f32x4 acc[4];
#pragma unroll
    for (int ct = 0; ct < 4; ++ct) {
        f32x4 z = {0.f, 0.f, 0.f, 0.f};
        acc[ct] = __builtin_amdgcn_mfma_f32_16x16x32_f16(Af[0], Bf[ct][0], z, 0, 0, 0);
        acc[ct] = __builtin_amdgcn_mfma_f32_16x16x32_f16(Af[1], Bf[ct][1], acc[ct], 0, 0, 0);
    }

#pragma unroll
    for (int j = 0; j < 4; ++j) {
        int rr = row0 + 4 * g16 + j;
        float di = rsqrtf((float)cnt[rr] + 1.0f);
#pragma unroll
        for (int ct = 0; ct < 4; ++ct)
            out[(size_t)rr * F + ct * 16 + r] = __float2half(acc[ct][j] * di);
    }
}

__device__ __forceinline__ float2 cvt2(unsigned int u) {
    __half2 h = *reinterpret_cast<__half2*>(&u);
    return __half22float2(h);
}

#define ACC8(u, wt)                                                          \
    {                                                                        \
        float2 p0 = cvt2((u).x), p1 = cvt2((u).y),                           \
               p2 = cvt2((u).z), p3 = cvt2((u).w);                           \
        a0 = fmaf(p0.x, wt, a0); a1 = fmaf(p0.y, wt, a1);                    \
        a2 = fmaf(p1.x, wt, a2); a3 = fmaf(p1.y, wt, a3);                    \
        a4 = fmaf(p2.x, wt, a4); a5 = fmaf(p2.y, wt, a5);                    \
        a6 = fmaf(p3.x, wt, a6); a7 = fmaf(p3.y, wt, a7);                    \
    }

// ---------------- fused aggregate + bias + BN + ReLU + pooled reduce(s) ----------------
// 4 dst nodes per wave (16 lanes each): 16 unconditional chunk loads in flight.
template<bool WRITE_OUT, bool POOL_X>
__global__ void k_agg_pool(const __half* __restrict__ hs, const int* __restrict__ cnt,
                           const int* __restrict__ bucket,
                           const int* __restrict__ batch,
                           const float* __restrict__ x,
                           const float* __restrict__ b, const float* __restrict__ gamma,
                           const float* __restrict__ beta, const float* __restrict__ mean,
                           const float* __restrict__ var,
                           float* __restrict__ out,
                           float* __restrict__ pooledX, float* __restrict__ pooledV) {
    __shared__ float prowV[16][64];
    __shared__ float prowX[16][64];
    __shared__ int pg[16];
    int w    = threadIdx.x >> 6;
    int lane = threadIdx.x & 63;
    int sub  = lane & 15;
    int nsel = lane >> 4;
    int esel = sub >> 3;
    int q    = sub & 7;
    int base = lane & 48;
    int nodeIdx = w * 4 + nsel;
    int d = blockIdx.x * 16 + nodeIdx;         // 6250*16 == N_NODES exactly
    const uint4* hs4 = (const uint4*)hs;

    int cdeg = cnt[d];
    int kk = cdeg > (DEG_CAP - 1) ? (DEG_CAP - 1) : cdeg;
    int nentF = kk + 1;
    int ev0 = (sub == 0) ? d : bucket[(size_t)d * DEG_CAP + sub - 1];   // entries 0..15
    int ev1 = bucket[(size_t)d * DEG_CAP + 15 + sub];                   // entries 16..31
    float4 xv = make_float4(0.f, 0.f, 0.f, 0.f);
    if (POOL_X) xv = ((const float4*)x)[(size_t)d * 16 + sub];
    int g = batch[d];

    float a0 = 0.f, a1 = 0.f, a2 = 0.f, a3 = 0.f,
          a4 = 0.f, a5 = 0.f, a6 = 0.f, a7 = 0.f;

#define SELA(i) int s##i; float w##i;                                        \
    { int t = 2 * (i) + esel; int c = __shfl(ev0, base + t);                 \
      s##i = (t < nentF) ? c : d; w##i = (t < nentF) ? 1.f : 0.f; }
#define SELB(i) int s##i; float w##i;                                        \
    { int t = 2 * (i) + esel; int c = __shfl(ev1, base + (t - 16));          \
      s##i = (t < nentF) ? c : d; w##i = (t < nentF) ? 1.f : 0.f; }
#define LD(i) uint4 u##i = hs4[(size_t)s##i * 8 + q];

    SELA(0) SELA(1) SELA(2) SELA(3) SELA(4) SELA(5) SELA(6) SELA(7)
    SELB(8) SELB(9) SELB(10) SELB(11) SELB(12) SELB(13) SELB(14) SELB(15)
    LD(0) LD(1) LD(2) LD(3) LD(4) LD(5) LD(6) LD(7)
    LD(8) LD(9) LD(10) LD(11) LD(12) LD(13) LD(14) LD(15)
    ACC8(u0,  w0)  ACC8(u1,  w1)  ACC8(u2,  w2)  ACC8(u3,  w3)
    ACC8(u4,  w4)  ACC8(u5,  w5)  ACC8(u6,  w6)  ACC8(u7,  w7)
    ACC8(u8,  w8)  ACC8(u9,  w9)  ACC8(u10, w10) ACC8(u11, w11)
    ACC8(u12, w12) ACC8(u13, w13) ACC8(u14, w14) ACC8(u15, w15)
#undef SELA
#undef SELB
#undef LD

    if (__any(nentF > 32)) {                   // rare heavy nodes (deg > 31)
        int evA = bucket[(size_t)d * DEG_CAP + 31 + sub];   // entries 32..47
        int evB = bucket[(size_t)d * DEG_CAP + 47 + sub];   // entries 48..63
#pragma unroll
        for (int i = 0; i < 16; ++i) {
            int t = 32 + 2 * i + esel;
            int cA = __shfl(evA, base + ((t - 32) & 15));
            int cB = __shfl(evB, base + ((t - 48) & 15));
            int c = (t < 48) ? cA : cB;
            int s = (t < nentF) ? c : d;
            uint4 uu = hs4[(size_t)s * 8 + q];
            float wt = (t < nentF) ? 1.f : 0.f;
            ACC8(uu, wt);
        }
    }

    a0 += __shfl_xor(a0, 8); a1 += __shfl_xor(a1, 8);
    a2 += __shfl_xor(a2, 8); a3 += __shfl_xor(a3, 8);
    a4 += __shfl_xor(a4, 8); a5 += __shfl_xor(a5, 8);
    a6 += __shfl_xor(a6, 8); a7 += __shfl_xor(a7, 8);

    if (sub < 8) {
        float di = rsqrtf((float)cdeg + 1.0f);
        const float4* b4  = (const float4*)b;
        const float4* m4  = (const float4*)mean;
        const float4* v4  = (const float4*)var;
        const float4* g4  = (const float4*)gamma;
        const float4* e4  = (const float4*)beta;
        float4 bb0 = b4[2 * q], bb1 = b4[2 * q + 1];
        float4 mm0 = m4[2 * q], mm1 = m4[2 * q + 1];
        float4 vv0 = v4[2 * q], vv1 = v4[2 * q + 1];
        float4 gg0 = g4[2 * q], gg1 = g4[2 * q + 1];
        float4 ee0 = e4[2 * q], ee1 = e4[2 * q + 1];
        float4 V0, V1;
        V0.x = fmaxf((di * a0 + bb0.x - mm0.x) * rsqrtf(vv0.x + EPS) * gg0.x + ee0.x, 0.f);
        V0.y = fmaxf((di * a1 + bb0.y - mm0.y) * rsqrtf(vv0.y + EPS) * gg0.y + ee0.y, 0.f);
        V0.z = fmaxf((di * a2 + bb0.z - mm0.z) * rsqrtf(vv0.z + EPS) * gg0.z + ee0.z, 0.f);
        V0.w = fmaxf((di * a3 + bb0.w - mm0.w) * rsqrtf(vv0.w + EPS) * gg0.w + ee0.w, 0.f);
        V1.x = fmaxf((di * a4 + bb1.x - mm1.x) * rsqrtf(vv1.x + EPS) * gg1.x + ee1.x, 0.f);
        V1.y = fmaxf((di * a5 + bb1.y - mm1.y) * rsqrtf(vv1.y + EPS) * gg1.y + ee1.y, 0.f);
        V1.z = fmaxf((di * a6 + bb1.z - mm1.z) * rsqrtf(vv1.z + EPS) * gg1.z + ee1.z, 0.f);
        V1.w = fmaxf((di * a7 + bb1.w - mm1.w) * rsqrtf(vv1.w + EPS) * gg1.w + ee1.w, 0.f);
        if (WRITE_OUT) {
            float4* o4 = (float4*)out;
            o4[(size_t)d * 16 + 2 * q]     = V0;
            o4[(size_t)d * 16 + 2 * q + 1] = V1;
        }
        float4* pv = (float4*)&prowV[nodeIdx][0];
        pv[2 * q]     = V0;
        pv[2 * q + 1] = V1;
    }
    if (POOL_X) ((float4*)&prowX[nodeIdx][0])[sub] = xv;
    if (sub == 0) pg[nodeIdx] = g;
    __syncthreads();

    int f2 = threadIdx.x & 63;
    for (int r = threadIdx.x >> 6; r < 16; r += 4) {
        int gg = pg[r];
        bool first = true;
        for (int r2 = 0; r2 < r; ++r2) if (pg[r2] == gg) first = false;
        if (first) {
            float a = 0.f, bx = 0.f;
            for (int r2 = r; r2 < 16; ++r2)
                if (pg[r2] == gg) { a += prowV[r2][f2]; if (POOL_X) bx += prowX[r2][f2]; }
            atomicAdd(&pooledV[gg * F + f2], a);
            if (POOL_X) atomicAdd(&pooledX[gg * F + f2], bx);
        }
    }
}

// ---------------- head ----------------
__global__ void k_head(const float* __restrict__ pooled, const float* __restrict__ headW,
                       const float* __restrict__ headb, float* __restrict__ out) {
    int idx = blockIdx.x * blockDim.x + threadIdx.x;   // 1024 = 64*16
    if (idx >= NUM_GRAPHS * 16) return;
    int g = idx >> 4, o = idx & 15;
    float acc = 0.f;
#pragma unroll
    for (int l = 0; l < 3; ++l) {
        const float* pl = pooled + (size_t)l * NUM_GRAPHS * F + (size_t)g * F;
        const float* wl = headW + (size_t)l * F * 16;
        float s = 0.f;
        for (int k = 0; k < F; ++k) s += pl[k] * wl[k * 16 + o];
        acc += s + headb[l * 16 + o];
    }
    out[idx] = acc;
}

extern "C" void kernel_launch(void* const* d_in, const int* in_sizes, int n_in,
                              void* d_out, int out_size, void* d_ws, size_t ws_size,
                              hipStream_t stream) {
    const float* x     = (const float*)d_in[0];
    const int*   ei    = (const int*)d_in[1];
    const int*   src   = ei;
    const int*   dst   = ei + N_EDGES;
    const int*   batch = (const int*)d_in[2];
    const float* convW = (const float*)d_in[3];
    const float* convb = (const float*)d_in[4];
    const float* gamma = (const float*)d_in[5];
    const float* beta  = (const float*)d_in[6];
    const float* mean  = (const float*)d_in[7];
    const float* var   = (const float*)d_in[8];
    const float* headW = (const float*)d_in[9];
    const float* headb = (const float*)d_in[10];
    float* out = (float*)d_out;

    char* p = (char*)d_ws;
    int*    cnt    = (int*)p;       p += sizeof(int) * N_NODES;
    int*    bucket = (int*)p;       p += sizeof(int) * (size_t)N_NODES * DEG_CAP;
    __half* hs     = (__half*)p;    p += sizeof(__half) * (size_t)N_NODES * F;
    float*  hA     = (float*)p;     p += sizeof(float) * (size_t)N_NODES * F;
    float*  pooled = (float*)p;     p += sizeof(float) * 3 * NUM_GRAPHS * F;
    int*    binCnt = (int*)p;       p += sizeof(int) * NBINS;
    int2*   bins   = (int2*)hA;     // alias: bins die before hA is first written

    const int B = 256;
    int gN   = (N_NODES + B - 1) / B;          // 391
    int gAgg = N_NODES / 16;                   // 6250 (4 nodes/wave, 16/block)

    k_init <<<gN, B, 0, stream>>>(pooled, binCnt);
    k_bin  <<<KB_BLOCKS, B, 0, stream>>>(src, dst, binCnt, bins);
    k_fill3<<<NBINS, B, 0, stream>>>(binCnt, bins, cnt, bucket);

    // ----- layer 0 (also pools x into rep0) -----
    k_gemm_mfma<<<GT_BLOCKS, B, 0, stream>>>(x, convW, cnt, hs);
    k_agg_pool<true, true><<<gAgg, B, 0, stream>>>(hs, cnt, bucket, batch, x, convb,
                                                   gamma, beta, mean, var,
                                                   hA, pooled, pooled + NUM_GRAPHS * F);

    // ----- layer 1 -----
    k_gemm_mfma<<<GT_BLOCKS, B, 0, stream>>>(hA, convW + F * F, cnt, hs);
    k_agg_pool<false, false><<<gAgg, B, 0, stream>>>(hs, cnt, bucket, batch, nullptr,
                                                     convb + F, gamma + F, beta + F,
                                                     mean + F, var + F,
                                                     nullptr, nullptr,
                                                     pooled + 2 * NUM_GRAPHS * F);

    // head
    k_head<<<(NUM_GRAPHS * 16 + B - 1) / B, B, 0, stream>>>(pooled, headW, headb, out);
}

// Round 17
// 156.704 us; speedup vs baseline: 1.9689x; 1.0542x over previous
//
#include <hip/hip_runtime.h>
#include <hip/hip_fp16.h>

#define N_NODES    100000
#define N_EDGES    1600000
#define NUM_GRAPHS 64
#define F          64
#define EPS        1e-5f
#define DEG_CAP    64
#define BIN_NODES  512
#define NBINS      ((N_NODES + BIN_NODES - 1) / BIN_NODES)   // 196
#define BIN_CAP    16000
#define KB_BLOCKS  128
#define KB_EDGES   (N_EDGES / KB_BLOCKS)    // 12500 edges per bin block

typedef __attribute__((ext_vector_type(8))) _Float16 f16x8;
typedef __attribute__((ext_vector_type(4))) float    f32x4;

// ---------------- init: zero pooled / binCnt ----------------
__global__ void k_init(float* pooled, int* binCnt) {
    int i = blockIdx.x * blockDim.x + threadIdx.x;
    if (i < 3 * NUM_GRAPHS * F) pooled[i] = 0.f;
    if (i < NBINS) binCnt[i] = 0;
}

// ---------------- phase 1: bin edges by 512-node dst group (dense rank writes) ----------------
__global__ void k_bin(const int* __restrict__ src, const int* __restrict__ dst,
                      int* __restrict__ binCnt, int2* __restrict__ bins) {
    __shared__ int bcnt[NBINS];
    __shared__ int bbase[NBINS];
    __shared__ int brun[NBINS];
    int t = threadIdx.x;
    for (int i = t; i < NBINS; i += 256) bcnt[i] = 0;
    __syncthreads();
    size_t e0 = (size_t)blockIdx.x * KB_EDGES;
    const int4* d4 = (const int4*)(dst + e0);
    const int4* s4 = (const int4*)(src + e0);
    const int NV = KB_EDGES / 4;
    for (int i = t; i < NV; i += 256) {
        int4 dv = d4[i];
        atomicAdd(&bcnt[dv.x / BIN_NODES], 1);
        atomicAdd(&bcnt[dv.y / BIN_NODES], 1);
        atomicAdd(&bcnt[dv.z / BIN_NODES], 1);
        atomicAdd(&bcnt[dv.w / BIN_NODES], 1);
    }
    __syncthreads();
    for (int i = t; i < NBINS; i += 256) {
        bbase[i] = atomicAdd(&binCnt[i], bcnt[i]);
        brun[i] = 0;
    }
    __syncthreads();
    for (int i = t; i < NV; i += 256) {
        int4 dv = d4[i];
        int4 sv = s4[i];
#define DO_E(dd, ss)                                                         \
        {                                                                    \
            int bn = (dd) / BIN_NODES;                                       \
            int r = atomicAdd(&brun[bn], 1);                                 \
            int off = bbase[bn] + r;                                         \
            if (off < BIN_CAP) bins[(size_t)bn * BIN_CAP + off] = make_int2((ss), (dd)); \
        }
        DO_E(dv.x, sv.x) DO_E(dv.y, sv.y) DO_E(dv.z, sv.z) DO_E(dv.w, sv.w)
#undef DO_E
    }
}

// ---------------- phase 2: LDS-staged bucket build, fully dense global writes ----------------
__global__ void __launch_bounds__(256, 1) k_fill3(const int* __restrict__ binCnt,
                        const int2* __restrict__ bins,
                        int* __restrict__ cnt, int* __restrict__ bucket) {
    __shared__ int lbucket[BIN_NODES * DEG_CAP];        // 128 KiB
    __shared__ int lcnt[BIN_NODES];
    int bn = blockIdx.x;
    int base = bn * BIN_NODES;
    int nnodes = N_NODES - base; if (nnodes > BIN_NODES) nnodes = BIN_NODES;
    int t = threadIdx.x;
    for (int i = t; i < BIN_NODES; i += 256) lcnt[i] = 0;
    __syncthreads();
    int n = binCnt[bn]; if (n > BIN_CAP) n = BIN_CAP;
    const int2* bin = bins + (size_t)bn * BIN_CAP;
    for (int i = t; i < n; i += 256) {
        int2 e = bin[i];
        int slot = atomicAdd(&lcnt[e.y - base], 1);
        if (slot < DEG_CAP) lbucket[(e.y - base) * DEG_CAP + slot] = e.x;
    }
    __syncthreads();
    int4* gb = (int4*)(bucket + (size_t)base * DEG_CAP);
    const int4* lb = (const int4*)lbucket;
    int nv = nnodes * (DEG_CAP / 4);
    for (int i = t; i < nv; i += 256) gb[i] = lb[i];
    for (int i = t; i < nnodes; i += 256) cnt[base + i] = lcnt[i];
}

// ---------------- MFMA GEMM: hs[r] = fp16((h[r] @ W) * rsqrt(cnt[r]+1)) ----------------
#define N_TILES (N_NODES / 16)                 // 6250
#define GT_BLOCKS ((N_TILES + 3) / 4)          // 1563
__global__ void k_gemm_mfma(const float* __restrict__ h, const float* __restrict__ W,
                            const int* __restrict__ cnt, __half* __restrict__ out) {
    __shared__ _Float16 Wh[64 * 64];
    int t = threadIdx.x;
    for (int i = t; i < 64 * 64; i += 256) Wh[i] = (_Float16)W[i];
    __syncthreads();
    int lane = t & 63, wv = t >> 6;
    int tile = blockIdx.x * 4 + wv;
    if (tile >= N_TILES) return;
    int row0 = tile * 16;
    int r   = lane & 15;
    int g16 = lane >> 4;
    int k0  = g16 * 8;

    f16x8 Bf[4][2];
#pragma unroll
    for (int ct = 0; ct < 4; ++ct)
#pragma unroll
        for (int ck = 0; ck < 2; ++ck)
#pragma unroll
            for (int i = 0; i < 8; ++i)
                Bf[ct][ck][i] = Wh[(32 * ck + k0 + i) * 64 + ct * 16 + r];

    f16x8 Af[2];
#pragma unroll
    for (int ck = 0; ck < 2; ++ck) {
        const float4* x4 = (const float4*)(h + (size_t)(row0 + r) * F + 32 * ck + k0);
        float4 p = x4[0], q = x4[1];
        Af[ck][0] = (_Float16)p.x; Af[ck][1] = (_Float16)p.y;
        Af[ck][2] = (_Float16)p.z; Af[ck][3] = (_Float16)p.w;
        Af[ck][4] = (_Float16)q.x; Af[ck][5] = (_Float16)q.y;
        Af[ck][6] = (_Float16)q.z; Af[ck][7] = (_Float16)q.w;
    }

    f32x4 acc[4];
#pragma unroll
    for (int ct = 0; ct < 4; ++ct) {
        f32x4 z = {0.f, 0.f, 0.f, 0.f};
        acc[ct] = __builtin_amdgcn_mfma_f32_16x16x32_f16(Af[0], Bf[ct][0], z, 0, 0, 0);
        acc[ct] = __builtin_amdgcn_mfma_f32_16x16x32_f16(Af[1], Bf[ct][1], acc[ct], 0, 0, 0);
    }

#pragma unroll
    for (int j = 0; j < 4; ++j) {
        int rr = row0 + 4 * g16 + j;
        float di = rsqrtf((float)cnt[rr] + 1.0f);
#pragma unroll
        for (int ct = 0; ct < 4; ++ct)
            out[(size_t)rr * F + ct * 16 + r] = __float2half(acc[ct][j] * di);
    }
}

__device__ __forceinline__ float2 cvt2(unsigned int u) {
    __half2 h = *reinterpret_cast<__half2*>(&u);
    return __half22float2(h);
}

#define ACC8(u, wt)                                                          \
    {                                                                        \
        float2 p0 = cvt2((u).x), p1 = cvt2((u).y),                           \
               p2 = cvt2((u).z), p3 = cvt2((u).w);                           \
        a0 = fmaf(p0.x, wt, a0); a1 = fmaf(p0.y, wt, a1);                    \
        a2 = fmaf(p1.x, wt, a2); a3 = fmaf(p1.y, wt, a3);                    \
        a4 = fmaf(p2.x, wt, a4); a5 = fmaf(p2.y, wt, a5);                    \
        a6 = fmaf(p3.x, wt, a6); a7 = fmaf(p3.y, wt, a7);                    \
    }

// ---------------- fused aggregate + bias + BN + ReLU + pool (+ optional next-layer GEMM) ----
// 4 dst nodes per wave; 16 unconditional chunk loads in flight.
// DO_GEMM: block's 16 finished rows (prowV) = one 16-row MFMA tile ->
// compute hs_next = fp16((row @ W1) * dinv) in-kernel, skipping the hA round trip.
template<bool POOL_X, bool DO_GEMM>
__global__ void k_agg_pool(const __half* __restrict__ hs, const int* __restrict__ cnt,
                           const int* __restrict__ bucket,
                           const int* __restrict__ batch,
                           const float* __restrict__ x,
                           const float* __restrict__ b, const float* __restrict__ gamma,
                           const float* __restrict__ beta, const float* __restrict__ mean,
                           const float* __restrict__ var,
                           const float* __restrict__ W1, __half* __restrict__ hs_next,
                           float* __restrict__ pooledX, float* __restrict__ pooledV) {
    __shared__ float prowV[16][64];
    __shared__ float prowX[16][64];
    __shared__ _Float16 Wh[64 * 64];
    __shared__ int pg[16];
    int tid  = threadIdx.x;
    int w    = tid >> 6;
    int lane = tid & 63;
    int sub  = lane & 15;
    int nsel = lane >> 4;
    int esel = sub >> 3;
    int q    = sub & 7;
    int base = lane & 48;
    int nodeIdx = w * 4 + nsel;
    int d = blockIdx.x * 16 + nodeIdx;         // 6250*16 == N_NODES exactly
    const uint4* hs4 = (const uint4*)hs;

    if (DO_GEMM)
        for (int i = tid; i < 64 * 64; i += 256) Wh[i] = (_Float16)W1[i];

    int cdeg = cnt[d];
    int kk = cdeg > (DEG_CAP - 1) ? (DEG_CAP - 1) : cdeg;
    int nentF = kk + 1;
    int ev0 = (sub == 0) ? d : bucket[(size_t)d * DEG_CAP + sub - 1];   // entries 0..15
    int ev1 = bucket[(size_t)d * DEG_CAP + 15 + sub];                   // entries 16..31
    float4 xv = make_float4(0.f, 0.f, 0.f, 0.f);
    if (POOL_X) xv = ((const float4*)x)[(size_t)d * 16 + sub];
    int g = batch[d];

    float a0 = 0.f, a1 = 0.f, a2 = 0.f, a3 = 0.f,
          a4 = 0.f, a5 = 0.f, a6 = 0.f, a7 = 0.f;

#define SELA(i) int s##i; float w##i;                                        \
    { int t = 2 * (i) + esel; int c = __shfl(ev0, base + t);                 \
      s##i = (t < nentF) ? c : d; w##i = (t < nentF) ? 1.f : 0.f; }
#define SELB(i) int s##i; float w##i;                                        \
    { int t = 2 * (i) + esel; int c = __shfl(ev1, base + (t - 16));          \
      s##i = (t < nentF) ? c : d; w##i = (t < nentF) ? 1.f : 0.f; }
#define LD(i) uint4 u##i = hs4[(size_t)s##i * 8 + q];

    SELA(0) SELA(1) SELA(2) SELA(3) SELA(4) SELA(5) SELA(6) SELA(7)
    SELB(8) SELB(9) SELB(10) SELB(11) SELB(12) SELB(13) SELB(14) SELB(15)
    LD(0) LD(1) LD(2) LD(3) LD(4) LD(5) LD(6) LD(7)
    LD(8) LD(9) LD(10) LD(11) LD(12) LD(13) LD(14) LD(15)
    ACC8(u0,  w0)  ACC8(u1,  w1)  ACC8(u2,  w2)  ACC8(u3,  w3)
    ACC8(u4,  w4)  ACC8(u5,  w5)  ACC8(u6,  w6)  ACC8(u7,  w7)
    ACC8(u8,  w8)  ACC8(u9,  w9)  ACC8(u10, w10) ACC8(u11, w11)
    ACC8(u12, w12) ACC8(u13, w13) ACC8(u14, w14) ACC8(u15, w15)
#undef SELA
#undef SELB
#undef LD

    if (__any(nentF > 32)) {                   // rare heavy nodes (deg > 31)
        int evA = bucket[(size_t)d * DEG_CAP + 31 + sub];   // entries 32..47
        int evB = bucket[(size_t)d * DEG_CAP + 47 + sub];   // entries 48..63
#pragma unroll
        for (int i = 0; i < 16; ++i) {
            int t = 32 + 2 * i + esel;
            int cA = __shfl(evA, base + ((t - 32) & 15));
            int cB = __shfl(evB, base + ((t - 48) & 15));
            int c = (t < 48) ? cA : cB;
            int s = (t < nentF) ? c : d;
            uint4 uu = hs4[(size_t)s * 8 + q];
            float wt = (t < nentF) ? 1.f : 0.f;
            ACC8(uu, wt);
        }
    }

    a0 += __shfl_xor(a0, 8); a1 += __shfl_xor(a1, 8);
    a2 += __shfl_xor(a2, 8); a3 += __shfl_xor(a3, 8);
    a4 += __shfl_xor(a4, 8); a5 += __shfl_xor(a5, 8);
    a6 += __shfl_xor(a6, 8); a7 += __shfl_xor(a7, 8);

    if (sub < 8) {
        float di = rsqrtf((float)cdeg + 1.0f);
        const float4* b4  = (const float4*)b;
        const float4* m4  = (const float4*)mean;
        const float4* v4  = (const float4*)var;
        const float4* g4  = (const float4*)gamma;
        const float4* e4  = (const float4*)beta;
        float4 bb0 = b4[2 * q], bb1 = b4[2 * q + 1];
        float4 mm0 = m4[2 * q], mm1 = m4[2 * q + 1];
        float4 vv0 = v4[2 * q], vv1 = v4[2 * q + 1];
        float4 gg0 = g4[2 * q], gg1 = g4[2 * q + 1];
        float4 ee0 = e4[2 * q], ee1 = e4[2 * q + 1];
        float4 V0, V1;
        V0.x = fmaxf((di * a0 + bb0.x - mm0.x) * rsqrtf(vv0.x + EPS) * gg0.x + ee0.x, 0.f);
        V0.y = fmaxf((di * a1 + bb0.y - mm0.y) * rsqrtf(vv0.y + EPS) * gg0.y + ee0.y, 0.f);
        V0.z = fmaxf((di * a2 + bb0.z - mm0.z) * rsqrtf(vv0.z + EPS) * gg0.z + ee0.z, 0.f);
        V0.w = fmaxf((di * a3 + bb0.w - mm0.w) * rsqrtf(vv0.w + EPS) * gg0.w + ee0.w, 0.f);
        V1.x = fmaxf((di * a4 + bb1.x - mm1.x) * rsqrtf(vv1.x + EPS) * gg1.x + ee1.x, 0.f);
        V1.y = fmaxf((di * a5 + bb1.y - mm1.y) * rsqrtf(vv1.y + EPS) * gg1.y + ee1.y, 0.f);
        V1.z = fmaxf((di * a6 + bb1.z - mm1.z) * rsqrtf(vv1.z + EPS) * gg1.z + ee1.z, 0.f);
        V1.w = fmaxf((di * a7 + bb1.w - mm1.w) * rsqrtf(vv1.w + EPS) * gg1.w + ee1.w, 0.f);
        float4* pv = (float4*)&prowV[nodeIdx][0];
        pv[2 * q]     = V0;
        pv[2 * q + 1] = V1;
    }
    if (POOL_X) ((float4*)&prowX[nodeIdx][0])[sub] = xv;
    if (sub == 0) pg[nodeIdx] = g;
    __syncthreads();

    // pooled reduction: one atomic row per distinct graph in this block
    int f2 = tid & 63;
    for (int r = tid >> 6; r < 16; r += 4) {
        int gg = pg[r];
        bool first = true;
        for (int r2 = 0; r2 < r; ++r2) if (pg[r2] == gg) first = false;
        if (first) {
            float a = 0.f, bx = 0.f;
            for (int r2 = r; r2 < 16; ++r2)
                if (pg[r2] == gg) { a += prowV[r2][f2]; if (POOL_X) bx += prowX[r2][f2]; }
            atomicAdd(&pooledV[gg * F + f2], a);
            if (POOL_X) atomicAdd(&pooledX[gg * F + f2], bx);
        }
    }

    if (DO_GEMM) {
        // wave w computes col-tile ct = w of hs_next rows blockIdx*16..+15
        int r   = lane & 15;
        int g16 = lane >> 4;
        int k0  = g16 * 8;
        f16x8 Af[2], Bf[2];
#pragma unroll
        for (int ck = 0; ck < 2; ++ck)
#pragma unroll
            for (int i = 0; i < 8; ++i) {
                Af[ck][i] = (_Float16)prowV[r][32 * ck + k0 + i];
                Bf[ck][i] = Wh[(32 * ck + k0 + i) * 64 + w * 16 + r];
            }
        f32x4 z = {0.f, 0.f, 0.f, 0.f};
        f32x4 acc = __builtin_amdgcn_mfma_f32_16x16x32_f16(Af[0], Bf[0], z, 0, 0, 0);
        acc = __builtin_amdgcn_mfma_f32_16x16x32_f16(Af[1], Bf[1], acc, 0, 0, 0);
#pragma unroll
        for (int j = 0; j < 4; ++j) {
            int rr = blockIdx.x * 16 + 4 * g16 + j;
            float di = rsqrtf((float)cnt[rr] + 1.0f);
            hs_next[(size_t)rr * F + w * 16 + r] = __float2half(acc[j] * di);
        }
    }
}

// ---------------- head ----------------
__global__ void k_head(const float* __restrict__ pooled, const float* __restrict__ headW,
                       const float* __restrict__ headb, float* __restrict__ out) {
    int idx = blockIdx.x * blockDim.x + threadIdx.x;   // 1024 = 64*16
    if (idx >= NUM_GRAPHS * 16) return;
    int g = idx >> 4, o = idx & 15;
    float acc = 0.f;
#pragma unroll
    for (int l = 0; l < 3; ++l) {
        const float* pl = pooled + (size_t)l * NUM_GRAPHS * F + (size_t)g * F;
        const float* wl = headW + (size_t)l * F * 16;
        float s = 0.f;
        for (int k = 0; k < F; ++k) s += pl[k] * wl[k * 16 + o];
        acc += s + headb[l * 16 + o];
    }
    out[idx] = acc;
}

extern "C" void kernel_launch(void* const* d_in, const int* in_sizes, int n_in,
                              void* d_out, int out_size, void* d_ws, size_t ws_size,
                              hipStream_t stream) {
    const float* x     = (const float*)d_in[0];
    const int*   ei    = (const int*)d_in[1];
    const int*   src   = ei;
    const int*   dst   = ei + N_EDGES;
    const int*   batch = (const int*)d_in[2];
    const float* convW = (const float*)d_in[3];
    const float* convb = (const float*)d_in[4];
    const float* gamma = (const float*)d_in[5];
    const float* beta  = (const float*)d_in[6];
    const float* mean  = (const float*)d_in[7];
    const float* var   = (const float*)d_in[8];
    const float* headW = (const float*)d_in[9];
    const float* headb = (const float*)d_in[10];
    float* out = (float*)d_out;

    char* p = (char*)d_ws;
    int*    cnt    = (int*)p;       p += sizeof(int) * N_NODES;
    int*    bucket = (int*)p;       p += sizeof(int) * (size_t)N_NODES * DEG_CAP;
    __half* hs     = (__half*)p;    p += sizeof(__half) * (size_t)N_NODES * F;
    char*   hAreg  = p;             p += sizeof(float) * (size_t)N_NODES * F;   // bins, then hs1
    float*  pooled = (float*)p;     p += sizeof(float) * 3 * NUM_GRAPHS * F;
    int*    binCnt = (int*)p;       p += sizeof(int) * NBINS;
    int2*   bins   = (int2*)hAreg;  // dies at end of k_fill3
    __half* hs1    = (__half*)hAreg; // written by fused agg0, read by agg1

    const int B = 256;
    int gInit = (3 * NUM_GRAPHS * F + B - 1) / B;   // 48
    int gAgg  = N_NODES / 16;                       // 6250

    k_init <<<gInit, B, 0, stream>>>(pooled, binCnt);
    k_bin  <<<KB_BLOCKS, B, 0, stream>>>(src, dst, binCnt, bins);
    k_fill3<<<NBINS, B, 0, stream>>>(binCnt, bins, cnt, bucket);

    // ----- layer 0: gemm0, then fused agg0 + pool(x, V) + gemm1 -----
    k_gemm_mfma<<<GT_BLOCKS, B, 0, stream>>>(x, convW, cnt, hs);
    k_agg_pool<true, true><<<gAgg, B, 0, stream>>>(hs, cnt, bucket, batch, x, convb,
                                                   gamma, beta, mean, var,
                                                   convW + F * F, hs1,
                                                   pooled, pooled + NUM_GRAPHS * F);

    // ----- layer 1: fused-gemm output -> agg1 + pool -----
    k_agg_pool<false, false><<<gAgg, B, 0, stream>>>(hs1, cnt, bucket, batch, nullptr,
                                                     convb + F, gamma + F, beta + F,
                                                     mean + F, var + F,
                                                     nullptr, nullptr,
                                                     nullptr, pooled + 2 * NUM_GRAPHS * F);

    // head
    k_head<<<(NUM_GRAPHS * 16 + B - 1) / B, B, 0, stream>>>(pooled, headW, headb, out);
}